// Round 12
// baseline (87.760 us; speedup 1.0000x reference)
//
#include <hip/hip_runtime.h>
#include <hip/hip_bf16.h>
#include <math.h>

#define D 2
#define B 64
#define P 512
#define NV 64
#define H 64
#define TW 128
#define NQ (B*NV + B)   // 4160

typedef short short8 __attribute__((ext_vector_type(8)));
typedef short short4v __attribute__((ext_vector_type(4)));
typedef float f32x4 __attribute__((ext_vector_type(4)));
typedef int   int4v  __attribute__((ext_vector_type(4)));

static __device__ __forceinline__ unsigned short f2bf(float f) {
    unsigned int u = __builtin_bit_cast(unsigned int, f);
    u += 0x7FFFu + ((u >> 16) & 1u);          // RNE
    return (unsigned short)(u >> 16);
}
static __device__ __forceinline__ unsigned int pk2bf(float a, float b) {
    __hip_bfloat162 h = __float22bfloat162_rn(make_float2(a, b));  // v_cvt_pk_bf16_f32
    unsigned int u;
    __builtin_memcpy(&u, &h, 4);              // a -> low 16, b -> high 16
    return u;
}

// ---------------- Kernel A: coeff (attention) ----------------
// 2 queries per block (2 waves each), 16 passes of 16 positions per wave.
// R12: NO per-pass cross-lane reduction — each lane stores its partial
// (sum over its n-slice) to s_part[qi][lg][prow]; the 4-way lg-sum happens
// once in the softmax phase. Pass body = geometry -> layer1 -> 2 MFMAs ->
// 4 short fma chains -> 1 LDS write. No shuffles/barriers in the loop.
// __launch_bounds__(256,3): VGPR cap 128. Never request 4+ waves (64-reg
// target -> 38MB scratch spill, R4/R7).
__global__ __launch_bounds__(256, 3) void coeff_kernel(
    const float* __restrict__ coords, const float* __restrict__ vel,
    const float* __restrict__ pos, const float* __restrict__ sigma,
    const float* __restrict__ aW0, const float* __restrict__ ab0,
    const float* __restrict__ aW1, const float* __restrict__ ab1,
    const float* __restrict__ aW2, const float* __restrict__ ab2,
    float* __restrict__ coeff_out)
{
    __shared__ unsigned short s_w1t[64*72];   // aW1^T [n][k] bf16, stride 72
    __shared__ float2 s_pos[P];
    __shared__ float  s_part[2][4][528];      // per-lane partials [qi][lg][pos], padded
    __shared__ float  s_plm[2][512];          // pl per position (mask input)

    const int tid  = threadIdx.x;
    const int lane = tid & 63, wid = tid >> 6;
    const int l15 = lane & 15, lg = lane >> 4;
    const int qi   = wid >> 1;                // query index within block (0/1)
    const int half = wid & 1;                 // position half (0: 0-255, 1: 256-511)
    const int q = blockIdx.x*2 + qi;

    // ---- block-wide staging (weights matrix + positions)
    for (int i = tid; i < H*H; i += 256) {
        const int k = i >> 6, n = i & 63;
        s_w1t[n*72 + k] = f2bf(aW1[i]);
    }
    {
        const float4 p4 = ((const float4*)pos)[tid];
        *(float4*)&s_pos[tid*2] = p4;
    }

    // ---- per-wave query scalars
    float x0, x1, v0, v1;
    {
        int b;
        if (q < B*NV) { b = q >> 6; const int j = q & 63;
            v0 = vel[2*j]; v1 = vel[2*j+1];
        } else { b = q - B*NV;
            v0 = coords[4*b+2]; v1 = coords[4*b+3];
        }
        x0 = coords[4*b]; x1 = coords[4*b+1];
    }
    const float rinv = rsqrtf(v0*v0 + v1*v1 + 1e-16f);
    const float a0 = v0*rinv, a1 = v1*rinv;

    // ---- per-lane collapsed layer1 weights for k-slice:
    // jj<8 -> k = lg*8+jj ; jj>=8 -> k = lg*8+(jj-8)+32
    float basev[16], w4v[16], w5v[16];
    #pragma unroll
    for (int jj = 0; jj < 16; ++jj) {
        const int k = lg*8 + (jj & 7) + (jj >> 3)*32;
        basev[jj] = ab0[k] + x0*aW0[k] + x1*aW0[64+k] + v0*aW0[128+k] + v1*aW0[192+k];
        w4v[jj]   = aW0[256+k];
        w5v[jj]   = aW0[320+k];
    }

    // ---- bias + w2 in registers (16-lane broadcast loads from global)
    f32x4 b1v[4], w2v[4];
    #pragma unroll
    for (int nt = 0; nt < 4; ++nt) {
        const int n0 = nt*16 + lg*4;
        b1v[nt] = *(const f32x4*)&ab1[n0];
        w2v[nt] = *(const f32x4*)&aW2[n0];
    }
    __syncthreads();

    // ---- A fragments: aW1^T rows = n, persistent
    short8 afrag[4][2];
    #pragma unroll
    for (int nt = 0; nt < 4; ++nt)
        #pragma unroll
        for (int ks = 0; ks < 2; ++ks)
            afrag[nt][ks] = *(const short8*)&s_w1t[(nt*16 + l15)*72 + ks*32 + lg*8];

    // ---- 16 passes of 16 positions; no shuffles, no barriers
    for (int ps = 0; ps < 16; ++ps) {
        const int prow = half*256 + ps*16 + l15;
        const float2 pxy = s_pos[prow];
        const float rx = x0 - pxy.x;
        const float ry = x1 - pxy.y;
        const float rd = __builtin_amdgcn_sqrtf(rx*rx + ry*ry + 1e-16f);
        const float pl = rx*a0 + ry*a1;
        const float al = __fdividef(pl, rd + 1e-8f);

        int4v wlo, whi;
        #pragma unroll
        for (int jp = 0; jp < 4; ++jp) {
            const float t0 = fmaxf(fmaf(pl, w5v[2*jp],   fmaf(al, w4v[2*jp],   basev[2*jp])),   0.f);
            const float t1 = fmaxf(fmaf(pl, w5v[2*jp+1], fmaf(al, w4v[2*jp+1], basev[2*jp+1])), 0.f);
            const float u0 = fmaxf(fmaf(pl, w5v[8+2*jp],   fmaf(al, w4v[8+2*jp],   basev[8+2*jp])),   0.f);
            const float u1 = fmaxf(fmaf(pl, w5v[8+2*jp+1], fmaf(al, w4v[8+2*jp+1], basev[8+2*jp+1])), 0.f);
            wlo[jp] = (int)pk2bf(t0, t1);
            whi[jp] = (int)pk2bf(u0, u1);
        }
        const short8 bf0 = __builtin_bit_cast(short8, wlo);
        const short8 bf1 = __builtin_bit_cast(short8, whi);

        // layer2 MFMAs + per-lane partial over this lane's n-slice
        // (4 independent fma chains; NO cross-lane reduce here)
        float s0 = 0.f, s1 = 0.f, s2 = 0.f, s3 = 0.f;
        #pragma unroll
        for (int nt = 0; nt < 4; ++nt) {
            f32x4 acc = b1v[nt];
            acc = __builtin_amdgcn_mfma_f32_16x16x32_bf16(afrag[nt][0], bf0, acc, 0, 0, 0);
            acc = __builtin_amdgcn_mfma_f32_16x16x32_bf16(afrag[nt][1], bf1, acc, 0, 0, 0);
            s0 += fmaxf(acc[0], 0.f) * w2v[nt][0];
            s1 += fmaxf(acc[1], 0.f) * w2v[nt][1];
            s2 += fmaxf(acc[2], 0.f) * w2v[nt][2];
            s3 += fmaxf(acc[3], 0.f) * w2v[nt][3];
        }
        s_part[qi][lg][prow] = (s0 + s1) + (s2 + s3);
        if (lg == 0) s_plm[qi][prow] = pl;
    }
    __syncthreads();

    // ---- lg-sum + masked softmax + sigma dot (both waves of the pair run
    // identical code on identical LDS data -> bit-identical; half==0 writes).
    const int p0 = lane*8;
    const float4 pa = *(const float4*)&s_plm[qi][p0];
    const float4 pb = *(const float4*)&s_plm[qi][p0+4];
    const float4 g0a = *(const float4*)&s_part[qi][0][p0];
    const float4 g1a = *(const float4*)&s_part[qi][1][p0];
    const float4 g2a = *(const float4*)&s_part[qi][2][p0];
    const float4 g3a = *(const float4*)&s_part[qi][3][p0];
    const float4 g0b = *(const float4*)&s_part[qi][0][p0+4];
    const float4 g1b = *(const float4*)&s_part[qi][1][p0+4];
    const float4 g2b = *(const float4*)&s_part[qi][2][p0+4];
    const float4 g3b = *(const float4*)&s_part[qi][3][p0+4];

    float lv[8];
    lv[0] = (pa.x > 0.f) ? (g0a.x+g1a.x)+(g2a.x+g3a.x) : -1e30f;
    lv[1] = (pa.y > 0.f) ? (g0a.y+g1a.y)+(g2a.y+g3a.y) : -1e30f;
    lv[2] = (pa.z > 0.f) ? (g0a.z+g1a.z)+(g2a.z+g3a.z) : -1e30f;
    lv[3] = (pa.w > 0.f) ? (g0a.w+g1a.w)+(g2a.w+g3a.w) : -1e30f;
    lv[4] = (pb.x > 0.f) ? (g0b.x+g1b.x)+(g2b.x+g3b.x) : -1e30f;
    lv[5] = (pb.y > 0.f) ? (g0b.y+g1b.y)+(g2b.y+g3b.y) : -1e30f;
    lv[6] = (pb.z > 0.f) ? (g0b.z+g1b.z)+(g2b.z+g3b.z) : -1e30f;
    lv[7] = (pb.w > 0.f) ? (g0b.w+g1b.w)+(g2b.w+g3b.w) : -1e30f;

    float m = fmaxf(fmaxf(fmaxf(lv[0], lv[1]), fmaxf(lv[2], lv[3])),
                    fmaxf(fmaxf(lv[4], lv[5]), fmaxf(lv[6], lv[7])));
    #pragma unroll
    for (int o = 32; o > 0; o >>= 1) m = fmaxf(m, __shfl_xor(m, o, 64));

    const float4 sg0 = *(const float4*)&sigma[p0];
    const float4 sg1 = *(const float4*)&sigma[p0 + 4];
    float S = 0.f, T = 0.f, e;
    e = __expf(lv[0] - m); S += e; T += e*sg0.x;
    e = __expf(lv[1] - m); S += e; T += e*sg0.y;
    e = __expf(lv[2] - m); S += e; T += e*sg0.z;
    e = __expf(lv[3] - m); S += e; T += e*sg0.w;
    e = __expf(lv[4] - m); S += e; T += e*sg1.x;
    e = __expf(lv[5] - m); S += e; T += e*sg1.y;
    e = __expf(lv[6] - m); S += e; T += e*sg1.z;
    e = __expf(lv[7] - m); S += e; T += e*sg1.w;
    #pragma unroll
    for (int o = 32; o > 0; o >>= 1) { S += __shfl_xor(S, o, 64); T += __shfl_xor(T, o, 64); }
    if (lane == 0 && half == 0) coeff_out[q] = __expf(-(T / S));
}

// ---------------- Kernel B: transport MLP ----------------
__global__ __launch_bounds__(128) void transport_kernel(
    const float* __restrict__ coords, const float* __restrict__ coordsp,
    const float* __restrict__ vel,
    const float* __restrict__ tW0, const float* __restrict__ tb0,
    const float* __restrict__ tW1, const float* __restrict__ tb1,
    const float* __restrict__ tW2, const float* __restrict__ tb2,
    const float* __restrict__ coeff_ws, float* __restrict__ cur_ws,
    float* __restrict__ g_ws)
{
    __shared__ float sh[TW];
    const int t = threadIdx.x, q = blockIdx.x;
    float in2, in3;
    int b;
    if (q < B*NV) { b = q >> 6; const int j = q & 63;
        in2 = vel[2*j]; in3 = vel[2*j+1];
    } else { b = q - B*NV;
        in2 = coords[4*b+2]; in3 = coords[4*b+3];
    }
    const float in0 = coords[4*b],  in1 = coords[4*b+1];
    const float p0 = coordsp[4*b],  p1 = coordsp[4*b+1];
    const float p2 = coordsp[4*b+2], p3 = coordsp[4*b+3];
    const float cf = coeff_ws[q];

    float h = tb0[t]
        + in0*tW0[t]       + in1*tW0[TW+t]   + in2*tW0[2*TW+t] + in3*tW0[3*TW+t]
        + p0 *tW0[4*TW+t]  + p1 *tW0[5*TW+t] + p2 *tW0[6*TW+t] + p3 *tW0[7*TW+t]
        + cf *tW0[8*TW+t];
    h = fmaxf(h, 0.f);
    sh[t] = h; __syncthreads();

    float h2 = tb1[t];
    for (int i = 0; i < TW; ++i) h2 += sh[i]*tW1[i*TW+t];
    h2 = fmaxf(h2, 0.f);
    __syncthreads(); sh[t] = h2; __syncthreads();

    float h3 = tb2[t];
    for (int i = 0; i < TW; ++i) h3 += sh[i]*tW2[i*TW+t];
    h3 = fmaxf(h3, 0.f);
    const float o = expf(h3);

    if (q < B*NV) cur_ws[q*TW + t] = o;
    else          g_ws[(q - B*NV)*TW + t] = o;
}

// ---------------- Kernel C: scattering recursion + output (MFMA) ----------------
__global__ __launch_bounds__(512) void scatter_kernel(
    const float* __restrict__ scat_k, const float* __restrict__ vw,
    const float* __restrict__ ssk,
    const float* __restrict__ rW, const float* __restrict__ rb,
    const float* __restrict__ fW, const float* __restrict__ fb,
    const float* __restrict__ cur_ws, const float* __restrict__ g_ws,
    float* __restrict__ out)
{
    __shared__ unsigned short s_At[128*72];
    __shared__ unsigned short s_r[64*136];
    __shared__ unsigned short s_rWt[128*136];
    __shared__ float s_wl[NV];
    __shared__ float s_fin[4*128];
    __shared__ float s_red[2];

    const int tid = threadIdx.x, b = blockIdx.x;
    const int lane = tid & 63, wid = tid >> 6;
    const int wm = wid & 3, wn = wid >> 2;
    const int l15 = lane & 15, lg = lane >> 4;
    const int irow = wm*16 + lg*4;

    if (tid < NV) s_wl[tid] = (1.f - scat_k[b*NV + tid]) * vw[tid];

    {
        const int w = tid & 127, j0 = tid >> 7;
        #pragma unroll
        for (int k = 0; k < 16; ++k) {
            const int j = j0 + 4*k;
            s_At[w*72 + j] = f2bf(cur_ws[(b*NV + j)*TW + w]);
        }
    }

    float areg[4][4], sreg[4][4];
    #pragma unroll
    for (int n = 0; n < 4; ++n) {
        const int wcol = wn*64 + n*16 + l15;
        #pragma unroll
        for (int rg = 0; rg < 4; ++rg) {
            const float v = cur_ws[(b*NV + irow + rg)*TW + wcol];
            areg[n][rg] = v; sreg[n][rg] = v;
        }
    }

    for (int l = 0; l < 2; ++l) {
        {
            const float* rWl = rW + l*TW*TW;
            const int w = tid & 127, u0 = (tid >> 7)*4;
            #pragma unroll
            for (int k = 0; k < 8; ++k) {
                const int u = u0 + 16*k;
                short4v pk;
                #pragma unroll
                for (int c = 0; c < 4; ++c) pk[c] = (short)f2bf(rWl[(u+c)*TW + w]);
                *(short4v*)&s_rWt[w*136 + u] = pk;
            }
        }
        __syncthreads();

        {
            short8 afrag[2];
            const int row = wm*16 + l15;
            #pragma unroll
            for (int ks = 0; ks < 2; ++ks) {
                const int k0 = ks*32 + lg*8;
                #pragma unroll
                for (int j = 0; j < 8; ++j) {
                    const float rv = (1.f - ssk[row*NV + k0 + j]) * vw[k0 + j];
                    afrag[ks][j] = (short)f2bf(rv);
                }
            }
            #pragma unroll
            for (int n = 0; n < 4; ++n) {
                const int col = wn*64 + n*16 + l15;
                f32x4 acc = {0.f, 0.f, 0.f, 0.f};
                #pragma unroll
                for (int ks = 0; ks < 2; ++ks) {
                    const short8 bfr = *(const short8*)&s_At[col*72 + ks*32 + lg*8];
                    acc = __builtin_amdgcn_mfma_f32_16x16x32_bf16(afrag[ks], bfr, acc, 0, 0, 0);
                }
                #pragma unroll
                for (int rg = 0; rg < 4; ++rg)
                    s_r[(irow + rg)*136 + col] = f2bf(acc[rg]);
            }
        }
        __syncthreads();

        {
            short8 af2[4];
            #pragma unroll
            for (int ks = 0; ks < 4; ++ks)
                af2[ks] = *(const short8*)&s_r[(wm*16 + l15)*136 + ks*32 + lg*8];
            #pragma unroll
            for (int n = 0; n < 4; ++n) {
                const int col = wn*64 + n*16 + l15;
                f32x4 acc = {0.f, 0.f, 0.f, 0.f};
                #pragma unroll
                for (int ks = 0; ks < 4; ++ks) {
                    const short8 bfr = *(const short8*)&s_rWt[col*136 + ks*32 + lg*8];
                    acc = __builtin_amdgcn_mfma_f32_16x16x32_bf16(af2[ks], bfr, acc, 0, 0, 0);
                }
                const float rbv = rb[l*TW + col];
                short4v pk;
                #pragma unroll
                for (int rg = 0; rg < 4; ++rg) {
                    areg[n][rg] += fmaxf(acc[rg] + rbv, 0.f);
                    sreg[n][rg] += areg[n][rg];
                    pk[rg] = (short)f2bf(areg[n][rg]);
                }
                *(short4v*)&s_At[col*72 + irow] = pk;
            }
        }
        __syncthreads();
    }

    float p[4];
    #pragma unroll
    for (int n = 0; n < 4; ++n) {
        float acc = 0.f;
        #pragma unroll
        for (int rg = 0; rg < 4; ++rg) acc += s_wl[irow + rg] * sreg[n][rg];
        acc += __shfl_xor(acc, 16, 64);
        acc += __shfl_xor(acc, 32, 64);
        p[n] = acc;
    }
    if (lg == 0) {
        #pragma unroll
        for (int n = 0; n < 4; ++n)
            s_fin[wm*128 + wn*64 + n*16 + l15] = p[n];
    }
    __syncthreads();

    if (tid < 128) {
        const int w = tid;
        const float tot = s_fin[w] + s_fin[128 + w] + s_fin[256 + w] + s_fin[384 + w];
        float pw = (g_ws[b*TW + w] + tot) * fW[w];
        #pragma unroll
        for (int o = 32; o > 0; o >>= 1) pw += __shfl_down(pw, o, 64);
        if ((tid & 63) == 0) s_red[tid >> 6] = pw;
    }
    __syncthreads();
    if (tid == 0) out[b] = s_red[0] + s_red[1] + fb[0];
}

extern "C" void kernel_launch(void* const* d_in, const int* in_sizes, int n_in,
                              void* d_out, int out_size, void* d_ws, size_t ws_size,
                              hipStream_t stream) {
    const float* coords  = (const float*)d_in[0];
    const float* coordsp = (const float*)d_in[1];
    const float* scatk   = (const float*)d_in[2];
    const float* pos     = (const float*)d_in[3];
    const float* sigma   = (const float*)d_in[4];
    const float* vel     = (const float*)d_in[5];
    const float* vw      = (const float*)d_in[6];
    const float* ssk     = (const float*)d_in[7];
    const float* aW0 = (const float*)d_in[8];
    const float* ab0 = (const float*)d_in[9];
    const float* aW1 = (const float*)d_in[10];
    const float* ab1 = (const float*)d_in[11];
    const float* aW2 = (const float*)d_in[12];
    const float* ab2 = (const float*)d_in[13];
    const float* tW0 = (const float*)d_in[14];
    const float* tb0 = (const float*)d_in[15];
    const float* tW1 = (const float*)d_in[16];
    const float* tb1 = (const float*)d_in[17];
    const float* tW2 = (const float*)d_in[18];
    const float* tb2 = (const float*)d_in[19];
    const float* rW  = (const float*)d_in[20];
    const float* rb  = (const float*)d_in[21];
    const float* fW  = (const float*)d_in[22];
    const float* fb  = (const float*)d_in[23];
    float* out = (float*)d_out;

    float* ws = (float*)d_ws;
    float* coeff_ws = ws;                    // NQ floats, padded
    float* cur_ws   = ws + 4224;             // B*NV*TW floats
    float* g_ws     = cur_ws + B*NV*TW;      // B*TW floats

    hipLaunchKernelGGL(coeff_kernel, dim3(NQ/2), dim3(256), 0, stream,
        coords, vel, pos, sigma, aW0, ab0, aW1, ab1, aW2, ab2, coeff_ws);
    hipLaunchKernelGGL(transport_kernel, dim3(NQ), dim3(128), 0, stream,
        coords, coordsp, vel, tW0, tb0, tW1, tb1, tW2, tb2, coeff_ws, cur_ws, g_ws);
    hipLaunchKernelGGL(scatter_kernel, dim3(B), dim3(512), 0, stream,
        scatk, vw, ssk, rW, rb, fW, fb, cur_ws, g_ws, out);
}

// Round 13
// 80.788 us; speedup vs baseline: 1.0863x; 1.0863x over previous
//
#include <hip/hip_runtime.h>
#include <hip/hip_bf16.h>
#include <math.h>

#define D 2
#define B 64
#define P 512
#define NV 64
#define H 64
#define TW 128
#define NQ (B*NV + B)   // 4160

typedef short short8 __attribute__((ext_vector_type(8)));
typedef short short4v __attribute__((ext_vector_type(4)));
typedef float f32x4 __attribute__((ext_vector_type(4)));
typedef int   int4v  __attribute__((ext_vector_type(4)));

static __device__ __forceinline__ unsigned short f2bf(float f) {
    unsigned int u = __builtin_bit_cast(unsigned int, f);
    u += 0x7FFFu + ((u >> 16) & 1u);          // RNE
    return (unsigned short)(u >> 16);
}
static __device__ __forceinline__ unsigned int pk2bf(float a, float b) {
    __hip_bfloat162 h = __float22bfloat162_rn(make_float2(a, b));  // v_cvt_pk_bf16_f32
    unsigned int u;
    __builtin_memcpy(&u, &h, 4);              // a -> low 16, b -> high 16
    return u;
}

// ---------------- Kernel A: coeff (attention) ----------------
// 2 queries per block (2 waves each), 16 passes of 16 positions per wave.
// R13: PIN all loop-invariant weights in VGPRs via empty asm ("+v") — the
// allocator was sinking the "hoisted" broadcast loads back into the hot loop
// (VGPR stayed ~80 across R8-R12 despite a ~112-reg declared persistent set),
// re-issuing ~10 dependent L1-latency loads per pass = ~2300cyc/pass stall.
// asm output can't be rematerialized -> values stay resident.
// __launch_bounds__(256,2): VGPR cap 256 (residency is ~2 waves/SIMD anyway).
// Never use min-waves>=4 (64-reg target -> 38MB scratch spill, R4/R7).
__global__ __launch_bounds__(256, 2) void coeff_kernel(
    const float* __restrict__ coords, const float* __restrict__ vel,
    const float* __restrict__ pos, const float* __restrict__ sigma,
    const float* __restrict__ aW0, const float* __restrict__ ab0,
    const float* __restrict__ aW1, const float* __restrict__ ab1,
    const float* __restrict__ aW2, const float* __restrict__ ab2,
    float* __restrict__ coeff_out)
{
    __shared__ unsigned short s_w1t[64*72];   // aW1^T [n][k] bf16, stride 72
    __shared__ float2 s_pos[P];
    __shared__ float  s_logit[2*P];           // per-query 512 masked logits

    const int tid  = threadIdx.x;
    const int lane = tid & 63, wid = tid >> 6;
    const int l15 = lane & 15, lg = lane >> 4;
    const int qi   = wid >> 1;                // query index within block (0/1)
    const int half = wid & 1;                 // position half (0: 0-255, 1: 256-511)
    const int q = blockIdx.x*2 + qi;

    // ---- block-wide staging (weights matrix + positions)
    for (int i = tid; i < H*H; i += 256) {
        const int k = i >> 6, n = i & 63;
        s_w1t[n*72 + k] = f2bf(aW1[i]);
    }
    {
        const float4 p4 = ((const float4*)pos)[tid];
        *(float4*)&s_pos[tid*2] = p4;
    }

    // ---- per-wave query scalars
    float x0, x1, v0, v1;
    {
        int b;
        if (q < B*NV) { b = q >> 6; const int j = q & 63;
            v0 = vel[2*j]; v1 = vel[2*j+1];
        } else { b = q - B*NV;
            v0 = coords[4*b+2]; v1 = coords[4*b+3];
        }
        x0 = coords[4*b]; x1 = coords[4*b+1];
    }
    const float rinv = rsqrtf(v0*v0 + v1*v1 + 1e-16f);
    const float a0 = v0*rinv, a1 = v1*rinv;

    // ---- per-lane collapsed layer1 weights for k-slice:
    // jj<8 -> k = lg*8+jj ; jj>=8 -> k = lg*8+(jj-8)+32
    float basev[16], w4v[16], w5v[16];
    #pragma unroll
    for (int jj = 0; jj < 16; ++jj) {
        const int k = lg*8 + (jj & 7) + (jj >> 3)*32;
        basev[jj] = ab0[k] + x0*aW0[k] + x1*aW0[64+k] + v0*aW0[128+k] + v1*aW0[192+k];
        w4v[jj]   = aW0[256+k];
        w5v[jj]   = aW0[320+k];
    }

    // ---- bias + w2 in registers (16-lane broadcast loads from global)
    f32x4 b1v[4], w2v[4];
    #pragma unroll
    for (int nt = 0; nt < 4; ++nt) {
        const int n0 = nt*16 + lg*4;
        b1v[nt] = *(const f32x4*)&ab1[n0];
        w2v[nt] = *(const f32x4*)&aW2[n0];
    }
    __syncthreads();

    // ---- A fragments: aW1^T rows = n, persistent
    short8 afrag[4][2];
    #pragma unroll
    for (int nt = 0; nt < 4; ++nt)
        #pragma unroll
        for (int ks = 0; ks < 2; ++ks)
            afrag[nt][ks] = *(const short8*)&s_w1t[(nt*16 + l15)*72 + ks*32 + lg*8];

    // ---- PIN loop-invariants in VGPRs: asm output is not rematerializable,
    // so the compiler cannot sink these loads/computations into the loop.
    #pragma unroll
    for (int jj = 0; jj < 16; ++jj)
        asm volatile("" : "+v"(basev[jj]), "+v"(w4v[jj]), "+v"(w5v[jj]));
    #pragma unroll
    for (int nt = 0; nt < 4; ++nt)
        asm volatile("" : "+v"(b1v[nt]), "+v"(w2v[nt]),
                          "+v"(afrag[nt][0]), "+v"(afrag[nt][1]));

    // ---- 16 passes of 16 positions; pos read software-pipelined by 1
    float2 pxy = s_pos[half*256 + l15];
    for (int ps = 0; ps < 16; ++ps) {
        const int prow = half*256 + ps*16 + l15;
        const float2 nxt = (ps < 15) ? s_pos[prow + 16] : pxy;

        const float rx = x0 - pxy.x;
        const float ry = x1 - pxy.y;
        const float rd = __builtin_amdgcn_sqrtf(rx*rx + ry*ry + 1e-16f);
        const float pl = rx*a0 + ry*a1;
        const float al = __fdividef(pl, rd + 1e-8f);

        int4v wlo, whi;
        #pragma unroll
        for (int jp = 0; jp < 4; ++jp) {
            const float t0 = fmaxf(fmaf(pl, w5v[2*jp],   fmaf(al, w4v[2*jp],   basev[2*jp])),   0.f);
            const float t1 = fmaxf(fmaf(pl, w5v[2*jp+1], fmaf(al, w4v[2*jp+1], basev[2*jp+1])), 0.f);
            const float u0 = fmaxf(fmaf(pl, w5v[8+2*jp],   fmaf(al, w4v[8+2*jp],   basev[8+2*jp])),   0.f);
            const float u1 = fmaxf(fmaf(pl, w5v[8+2*jp+1], fmaf(al, w4v[8+2*jp+1], basev[8+2*jp+1])), 0.f);
            wlo[jp] = (int)pk2bf(t0, t1);
            whi[jp] = (int)pk2bf(u0, u1);
        }
        const short8 bf0 = __builtin_bit_cast(short8, wlo);
        const short8 bf1 = __builtin_bit_cast(short8, whi);

        float ssum = 0.f;
        #pragma unroll
        for (int nt = 0; nt < 4; ++nt) {
            f32x4 acc = b1v[nt];                      // bias C-init from registers
            acc = __builtin_amdgcn_mfma_f32_16x16x32_bf16(afrag[nt][0], bf0, acc, 0, 0, 0);
            acc = __builtin_amdgcn_mfma_f32_16x16x32_bf16(afrag[nt][1], bf1, acc, 0, 0, 0);
            ssum += fmaxf(acc[0], 0.f) * w2v[nt][0];
            ssum += fmaxf(acc[1], 0.f) * w2v[nt][1];
            ssum += fmaxf(acc[2], 0.f) * w2v[nt][2];
            ssum += fmaxf(acc[3], 0.f) * w2v[nt][3];
        }
        ssum += __shfl_xor(ssum, 16, 64);
        ssum += __shfl_xor(ssum, 32, 64);
        if (lane < 16) s_logit[qi*512 + prow] = (pl > 0.f) ? ssum : -1e30f;
        pxy = nxt;
    }
    __syncthreads();

    // ---- softmax + sigma dot, computed redundantly by both waves of the pair
    // (identical instruction stream on identical data -> bit-identical result).
    const float* lgb = &s_logit[qi*512];
    const float4 l0 = *(const float4*)&lgb[lane*8];
    const float4 l1 = *(const float4*)&lgb[lane*8 + 4];
    float m = fmaxf(fmaxf(fmaxf(l0.x, l0.y), fmaxf(l0.z, l0.w)),
                    fmaxf(fmaxf(l1.x, l1.y), fmaxf(l1.z, l1.w)));
    #pragma unroll
    for (int o = 32; o > 0; o >>= 1) m = fmaxf(m, __shfl_xor(m, o, 64));

    const float4 g0 = *(const float4*)&sigma[lane*8];
    const float4 g1 = *(const float4*)&sigma[lane*8 + 4];
    float S = 0.f, T = 0.f, e;
    e = __expf(l0.x - m); S += e; T += e*g0.x;
    e = __expf(l0.y - m); S += e; T += e*g0.y;
    e = __expf(l0.z - m); S += e; T += e*g0.z;
    e = __expf(l0.w - m); S += e; T += e*g0.w;
    e = __expf(l1.x - m); S += e; T += e*g1.x;
    e = __expf(l1.y - m); S += e; T += e*g1.y;
    e = __expf(l1.z - m); S += e; T += e*g1.z;
    e = __expf(l1.w - m); S += e; T += e*g1.w;
    #pragma unroll
    for (int o = 32; o > 0; o >>= 1) { S += __shfl_xor(S, o, 64); T += __shfl_xor(T, o, 64); }
    if (lane == 0 && half == 0) coeff_out[q] = __expf(-(T / S));
}

// ---------------- Kernel B: transport MLP ----------------
__global__ __launch_bounds__(128) void transport_kernel(
    const float* __restrict__ coords, const float* __restrict__ coordsp,
    const float* __restrict__ vel,
    const float* __restrict__ tW0, const float* __restrict__ tb0,
    const float* __restrict__ tW1, const float* __restrict__ tb1,
    const float* __restrict__ tW2, const float* __restrict__ tb2,
    const float* __restrict__ coeff_ws, float* __restrict__ cur_ws,
    float* __restrict__ g_ws)
{
    __shared__ float sh[TW];
    const int t = threadIdx.x, q = blockIdx.x;
    float in2, in3;
    int b;
    if (q < B*NV) { b = q >> 6; const int j = q & 63;
        in2 = vel[2*j]; in3 = vel[2*j+1];
    } else { b = q - B*NV;
        in2 = coords[4*b+2]; in3 = coords[4*b+3];
    }
    const float in0 = coords[4*b],  in1 = coords[4*b+1];
    const float p0 = coordsp[4*b],  p1 = coordsp[4*b+1];
    const float p2 = coordsp[4*b+2], p3 = coordsp[4*b+3];
    const float cf = coeff_ws[q];

    float h = tb0[t]
        + in0*tW0[t]       + in1*tW0[TW+t]   + in2*tW0[2*TW+t] + in3*tW0[3*TW+t]
        + p0 *tW0[4*TW+t]  + p1 *tW0[5*TW+t] + p2 *tW0[6*TW+t] + p3 *tW0[7*TW+t]
        + cf *tW0[8*TW+t];
    h = fmaxf(h, 0.f);
    sh[t] = h; __syncthreads();

    float h2 = tb1[t];
    for (int i = 0; i < TW; ++i) h2 += sh[i]*tW1[i*TW+t];
    h2 = fmaxf(h2, 0.f);
    __syncthreads(); sh[t] = h2; __syncthreads();

    float h3 = tb2[t];
    for (int i = 0; i < TW; ++i) h3 += sh[i]*tW2[i*TW+t];
    h3 = fmaxf(h3, 0.f);
    const float o = expf(h3);

    if (q < B*NV) cur_ws[q*TW + t] = o;
    else          g_ws[(q - B*NV)*TW + t] = o;
}

// ---------------- Kernel C: scattering recursion + output (MFMA) ----------------
__global__ __launch_bounds__(512) void scatter_kernel(
    const float* __restrict__ scat_k, const float* __restrict__ vw,
    const float* __restrict__ ssk,
    const float* __restrict__ rW, const float* __restrict__ rb,
    const float* __restrict__ fW, const float* __restrict__ fb,
    const float* __restrict__ cur_ws, const float* __restrict__ g_ws,
    float* __restrict__ out)
{
    __shared__ unsigned short s_At[128*72];
    __shared__ unsigned short s_r[64*136];
    __shared__ unsigned short s_rWt[128*136];
    __shared__ float s_wl[NV];
    __shared__ float s_fin[4*128];
    __shared__ float s_red[2];

    const int tid = threadIdx.x, b = blockIdx.x;
    const int lane = tid & 63, wid = tid >> 6;
    const int wm = wid & 3, wn = wid >> 2;
    const int l15 = lane & 15, lg = lane >> 4;
    const int irow = wm*16 + lg*4;

    if (tid < NV) s_wl[tid] = (1.f - scat_k[b*NV + tid]) * vw[tid];

    {
        const int w = tid & 127, j0 = tid >> 7;
        #pragma unroll
        for (int k = 0; k < 16; ++k) {
            const int j = j0 + 4*k;
            s_At[w*72 + j] = f2bf(cur_ws[(b*NV + j)*TW + w]);
        }
    }

    float areg[4][4], sreg[4][4];
    #pragma unroll
    for (int n = 0; n < 4; ++n) {
        const int wcol = wn*64 + n*16 + l15;
        #pragma unroll
        for (int rg = 0; rg < 4; ++rg) {
            const float v = cur_ws[(b*NV + irow + rg)*TW + wcol];
            areg[n][rg] = v; sreg[n][rg] = v;
        }
    }

    for (int l = 0; l < 2; ++l) {
        {
            const float* rWl = rW + l*TW*TW;
            const int w = tid & 127, u0 = (tid >> 7)*4;
            #pragma unroll
            for (int k = 0; k < 8; ++k) {
                const int u = u0 + 16*k;
                short4v pk;
                #pragma unroll
                for (int c = 0; c < 4; ++c) pk[c] = (short)f2bf(rWl[(u+c)*TW + w]);
                *(short4v*)&s_rWt[w*136 + u] = pk;
            }
        }
        __syncthreads();

        {
            short8 afrag[2];
            const int row = wm*16 + l15;
            #pragma unroll
            for (int ks = 0; ks < 2; ++ks) {
                const int k0 = ks*32 + lg*8;
                #pragma unroll
                for (int j = 0; j < 8; ++j) {
                    const float rv = (1.f - ssk[row*NV + k0 + j]) * vw[k0 + j];
                    afrag[ks][j] = (short)f2bf(rv);
                }
            }
            #pragma unroll
            for (int n = 0; n < 4; ++n) {
                const int col = wn*64 + n*16 + l15;
                f32x4 acc = {0.f, 0.f, 0.f, 0.f};
                #pragma unroll
                for (int ks = 0; ks < 2; ++ks) {
                    const short8 bfr = *(const short8*)&s_At[col*72 + ks*32 + lg*8];
                    acc = __builtin_amdgcn_mfma_f32_16x16x32_bf16(afrag[ks], bfr, acc, 0, 0, 0);
                }
                #pragma unroll
                for (int rg = 0; rg < 4; ++rg)
                    s_r[(irow + rg)*136 + col] = f2bf(acc[rg]);
            }
        }
        __syncthreads();

        {
            short8 af2[4];
            #pragma unroll
            for (int ks = 0; ks < 4; ++ks)
                af2[ks] = *(const short8*)&s_r[(wm*16 + l15)*136 + ks*32 + lg*8];
            #pragma unroll
            for (int n = 0; n < 4; ++n) {
                const int col = wn*64 + n*16 + l15;
                f32x4 acc = {0.f, 0.f, 0.f, 0.f};
                #pragma unroll
                for (int ks = 0; ks < 4; ++ks) {
                    const short8 bfr = *(const short8*)&s_rWt[col*136 + ks*32 + lg*8];
                    acc = __builtin_amdgcn_mfma_f32_16x16x32_bf16(af2[ks], bfr, acc, 0, 0, 0);
                }
                const float rbv = rb[l*TW + col];
                short4v pk;
                #pragma unroll
                for (int rg = 0; rg < 4; ++rg) {
                    areg[n][rg] += fmaxf(acc[rg] + rbv, 0.f);
                    sreg[n][rg] += areg[n][rg];
                    pk[rg] = (short)f2bf(areg[n][rg]);
                }
                *(short4v*)&s_At[col*72 + irow] = pk;
            }
        }
        __syncthreads();
    }

    float p[4];
    #pragma unroll
    for (int n = 0; n < 4; ++n) {
        float acc = 0.f;
        #pragma unroll
        for (int rg = 0; rg < 4; ++rg) acc += s_wl[irow + rg] * sreg[n][rg];
        acc += __shfl_xor(acc, 16, 64);
        acc += __shfl_xor(acc, 32, 64);
        p[n] = acc;
    }
    if (lg == 0) {
        #pragma unroll
        for (int n = 0; n < 4; ++n)
            s_fin[wm*128 + wn*64 + n*16 + l15] = p[n];
    }
    __syncthreads();

    if (tid < 128) {
        const int w = tid;
        const float tot = s_fin[w] + s_fin[128 + w] + s_fin[256 + w] + s_fin[384 + w];
        float pw = (g_ws[b*TW + w] + tot) * fW[w];
        #pragma unroll
        for (int o = 32; o > 0; o >>= 1) pw += __shfl_down(pw, o, 64);
        if ((tid & 63) == 0) s_red[tid >> 6] = pw;
    }
    __syncthreads();
    if (tid == 0) out[b] = s_red[0] + s_red[1] + fb[0];
}

extern "C" void kernel_launch(void* const* d_in, const int* in_sizes, int n_in,
                              void* d_out, int out_size, void* d_ws, size_t ws_size,
                              hipStream_t stream) {
    const float* coords  = (const float*)d_in[0];
    const float* coordsp = (const float*)d_in[1];
    const float* scatk   = (const float*)d_in[2];
    const float* pos     = (const float*)d_in[3];
    const float* sigma   = (const float*)d_in[4];
    const float* vel     = (const float*)d_in[5];
    const float* vw      = (const float*)d_in[6];
    const float* ssk     = (const float*)d_in[7];
    const float* aW0 = (const float*)d_in[8];
    const float* ab0 = (const float*)d_in[9];
    const float* aW1 = (const float*)d_in[10];
    const float* ab1 = (const float*)d_in[11];
    const float* aW2 = (const float*)d_in[12];
    const float* ab2 = (const float*)d_in[13];
    const float* tW0 = (const float*)d_in[14];
    const float* tb0 = (const float*)d_in[15];
    const float* tW1 = (const float*)d_in[16];
    const float* tb1 = (const float*)d_in[17];
    const float* tW2 = (const float*)d_in[18];
    const float* tb2 = (const float*)d_in[19];
    const float* rW  = (const float*)d_in[20];
    const float* rb  = (const float*)d_in[21];
    const float* fW  = (const float*)d_in[22];
    const float* fb  = (const float*)d_in[23];
    float* out = (float*)d_out;

    float* ws = (float*)d_ws;
    float* coeff_ws = ws;                    // NQ floats, padded
    float* cur_ws   = ws + 4224;             // B*NV*TW floats
    float* g_ws     = cur_ws + B*NV*TW;      // B*TW floats

    hipLaunchKernelGGL(coeff_kernel, dim3(NQ/2), dim3(256), 0, stream,
        coords, vel, pos, sigma, aW0, ab0, aW1, ab1, aW2, ab2, coeff_ws);
    hipLaunchKernelGGL(transport_kernel, dim3(NQ), dim3(128), 0, stream,
        coords, coordsp, vel, tW0, tb0, tW1, tb1, tW2, tb2, coeff_ws, cur_ws, g_ws);
    hipLaunchKernelGGL(scatter_kernel, dim3(B), dim3(512), 0, stream,
        scatk, vw, ssk, rW, rb, fW, fb, cur_ws, g_ws, out);
}